// Round 1
// baseline (993.127 us; speedup 1.0000x reference)
//
#include <hip/hip_runtime.h>
#include <math.h>

#define Bh 8
#define Lh 64
#define Dh 768
#define Fh 50
#define Ph 49
#define Ah 49
#define Nh 20000
#define Ch 36

// ---------------- text = lang @ W_text.T + b_text ----------------
// grid: 8*32 blocks (b, l-tile of 2), 256 threads; thread computes 3 d's x 2 l's
__global__ __launch_bounds__(256) void k_text(const float* __restrict__ lang,
                                              const float* __restrict__ Wt,
                                              const float* __restrict__ bt,
                                              float* __restrict__ text) {
    int b  = blockIdx.x >> 5;
    int l0 = (blockIdx.x & 31) * 2;
    int tid = threadIdx.x;
    __shared__ float ls[2][Dh];
    for (int i = tid; i < 2 * Dh; i += 256)
        ls[i / Dh][i % Dh] = lang[((size_t)(b * Lh + l0 + i / Dh)) * Dh + (i % Dh)];
    __syncthreads();
    float acc[2][3] = {{0.f, 0.f, 0.f}, {0.f, 0.f, 0.f}};
    for (int k = 0; k < Dh; k += 4) {
        float4 v0 = *(const float4*)&ls[0][k];
        float4 v1 = *(const float4*)&ls[1][k];
#pragma unroll
        for (int j = 0; j < 3; ++j) {
            int d = tid + j * 256;
            float4 wv = *(const float4*)&Wt[(size_t)d * Dh + k];
            acc[0][j] += wv.x * v0.x + wv.y * v0.y + wv.z * v0.z + wv.w * v0.w;
            acc[1][j] += wv.x * v1.x + wv.y * v1.y + wv.z * v1.z + wv.w * v1.w;
        }
    }
#pragma unroll
    for (int li = 0; li < 2; ++li)
#pragma unroll
        for (int j = 0; j < 3; ++j) {
            int d = tid + j * 256;
            text[((size_t)(b * Lh + l0 + li)) * Dh + d] = acc[li][j] + bt[d];
        }
}

// ---------------- target = lang_cls @ W_in.T ----------------
__global__ void k_target(const float* __restrict__ lang_cls, const float* __restrict__ W_in,
                         float* __restrict__ tgt) {
    int b = blockIdx.x, a = threadIdx.x;
    if (a < Ah) {
        float s = 0.f;
        for (int k = 0; k < Ah; ++k) s += lang_cls[b * Ah + k] * W_in[a * Ah + k];
        tgt[b * Ah + a] = s;
    }
}

// ---------------- frames attention path -> out[b, 0..F) ----------------
__global__ __launch_bounds__(256) void k_frames(const float* __restrict__ frames,
                                                const float* __restrict__ lang_cls,
                                                const float* __restrict__ tgt_ws,
                                                const float* __restrict__ W_out,
                                                const float* __restrict__ W_fc2,
                                                const float* __restrict__ b_fc2,
                                                float* __restrict__ out) {
    int b = blockIdx.x / Fh, f = blockIdx.x % Fh;
    int tid = threadIdx.x;
    __shared__ float fr[Ph * Ah];
    __shared__ float tg[Ah], cl[Ah], at[Ph], wc[Ah], af[Ah];
    const float* fp = frames + ((size_t)(b * Fh + f)) * (Ph * Ah);
    for (int i = tid; i < Ph * Ah; i += 256) fr[i] = fp[i];
    if (tid < Ah) { tg[tid] = tgt_ws[b * Ah + tid]; cl[tid] = lang_cls[b * Ah + tid]; }
    __syncthreads();
    if (tid < Ph) {
        float s = 0.f;
        for (int a = 0; a < Ah; ++a) s += fr[tid * Ah + a] * tg[a];
        at[tid] = s;
    }
    __syncthreads();
    if (tid < 64) {
        float raw = (tid < Ph) ? at[tid] : -3.4e38f;
        float v = raw;
        for (int m = 32; m; m >>= 1) v = fmaxf(v, __shfl_xor(v, m));
        float e = (tid < Ph) ? expf(raw - v) : 0.f;
        float s = e;
        for (int m = 32; m; m >>= 1) s += __shfl_xor(s, m);
        if (tid < Ph) at[tid] = e / s;
    }
    __syncthreads();
    if (tid < Ah) {
        float s = 0.f;
        for (int p = 0; p < Ph; ++p) s += at[p] * fr[p * Ah + tid];
        wc[tid] = s;
    }
    __syncthreads();
    if (tid < Ah) {
        float s = 0.f;
        for (int a = 0; a < Ah; ++a)
            s += wc[a] * W_out[tid * (2 * Ah) + a] + cl[a] * W_out[tid * (2 * Ah) + Ah + a];
        af[tid] = tanhf(s);
    }
    __syncthreads();
    for (int d = tid; d < Dh; d += 256) {
        float s = b_fc2[d];
        for (int j = 0; j < Ah; ++j) s += af[j] * W_fc2[d * Ah + j];
        out[((size_t)(b * (Fh + Ch) + f)) * Dh + d] = s;
    }
}

// ---------------- w[b,n] = max_l dot(grid_fts[b,n], text[b,l]) ----------------
// 64x64 output tile, K-tiled by 64. LDS layout [k][pt] (pad 68) -> ds_read_b128 operands.
__global__ __launch_bounds__(256) void k_w(const float* __restrict__ grid,
                                           const float* __restrict__ text,
                                           float* __restrict__ w) {
    __shared__ float As[64][68];
    __shared__ float Bs[64][68];
    int b = blockIdx.y;
    int n0 = blockIdx.x * 64;
    int tid = threadIdx.x;
    int tp = tid >> 4, tl = tid & 15;
    float c[4][4] = {};
    const float* tb = text + (size_t)b * Lh * Dh;
    for (int kt = 0; kt < Dh; kt += 64) {
#pragma unroll
        for (int r = 0; r < 4; ++r) {
            int pt = tp + 16 * r;  // row 0..63
            int n = n0 + pt; if (n >= Nh) n = Nh - 1;
            float4 av = *(const float4*)&grid[((size_t)(b * Nh + n)) * Dh + kt + tl * 4];
            As[tl * 4 + 0][pt] = av.x; As[tl * 4 + 1][pt] = av.y;
            As[tl * 4 + 2][pt] = av.z; As[tl * 4 + 3][pt] = av.w;
            float4 bv = *(const float4*)&tb[(size_t)pt * Dh + kt + tl * 4];
            Bs[tl * 4 + 0][pt] = bv.x; Bs[tl * 4 + 1][pt] = bv.y;
            Bs[tl * 4 + 2][pt] = bv.z; Bs[tl * 4 + 3][pt] = bv.w;
        }
        __syncthreads();
#pragma unroll 8
        for (int k = 0; k < 64; ++k) {
            float4 a  = *(const float4*)&As[k][tp << 2];
            float4 bb = *(const float4*)&Bs[k][tl << 2];
            c[0][0] += a.x * bb.x; c[0][1] += a.x * bb.y; c[0][2] += a.x * bb.z; c[0][3] += a.x * bb.w;
            c[1][0] += a.y * bb.x; c[1][1] += a.y * bb.y; c[1][2] += a.y * bb.z; c[1][3] += a.y * bb.w;
            c[2][0] += a.z * bb.x; c[2][1] += a.z * bb.y; c[2][2] += a.z * bb.z; c[2][3] += a.z * bb.w;
            c[3][0] += a.w * bb.x; c[3][1] += a.w * bb.y; c[3][2] += a.w * bb.z; c[3][3] += a.w * bb.w;
        }
        __syncthreads();
    }
#pragma unroll
    for (int i = 0; i < 4; ++i) {
        float v = fmaxf(fmaxf(c[i][0], c[i][1]), fmaxf(c[i][2], c[i][3]));
        v = fmaxf(v, __shfl_xor(v, 1));
        v = fmaxf(v, __shfl_xor(v, 2));
        v = fmaxf(v, __shfl_xor(v, 4));
        v = fmaxf(v, __shfl_xor(v, 8));
        int n = n0 + tp * 4 + i;
        if (tl == 0 && n < Nh) w[b * Nh + n] = v;
    }
}

// ---------------- per-cell max and exp-sum ----------------
__global__ __launch_bounds__(256) void k_mden(const float* __restrict__ w,
                                              const int* __restrict__ gi,
                                              float* __restrict__ m_ws,
                                              float* __restrict__ den_ws) {
    int b = blockIdx.x, tid = threadIdx.x;
    __shared__ unsigned mu[Ch];
    __shared__ float dn[Ch];
    __shared__ float mf[Ch];
    if (tid < Ch) { mu[tid] = 0u; dn[tid] = 0.f; }
    __syncthreads();
    for (int n = tid; n < Nh; n += 256) {
        float v = w[b * Nh + n];
        unsigned u = __float_as_uint(v);
        u = (u & 0x80000000u) ? ~u : (u | 0x80000000u);
        atomicMax(&mu[gi[b * Nh + n]], u);
    }
    __syncthreads();
    if (tid < Ch) {
        unsigned u = mu[tid];
        mf[tid] = (u == 0u) ? 0.f
                            : ((u & 0x80000000u) ? __uint_as_float(u ^ 0x80000000u)
                                                 : __uint_as_float(~u));
    }
    __syncthreads();
    for (int n = tid; n < Nh; n += 256) {
        int c = gi[b * Nh + n];
        atomicAdd(&dn[c], expf(w[b * Nh + n] - mf[c]));
    }
    __syncthreads();
    if (tid < Ch) { m_ws[b * Ch + tid] = mf[tid]; den_ws[b * Ch + tid] = dn[tid]; }
}

// ---------------- p[b,n] ----------------
__global__ __launch_bounds__(256) void k_p(const float* __restrict__ w,
                                           const int* __restrict__ gi,
                                           const float* __restrict__ m_ws,
                                           const float* __restrict__ den_ws,
                                           float* __restrict__ p) {
    int idx = blockIdx.x * 256 + threadIdx.x;  // 625*256 = 160000 exact
    int b = idx / Nh;
    int c = gi[idx];
    float den = den_ws[b * Ch + c];
    p[idx] = (den > 0.f) ? expf(w[idx] - m_ws[b * Ch + c]) / den : 0.f;
}

// ---------------- segment weighted sums (partials) ----------------
// grid: (16 chunks, 3 d-thirds, 8 b). LDS acc[36][256]; wave-per-point; skip p<=1e-12.
__global__ __launch_bounds__(256) void k_S(const float* __restrict__ grid,
                                           const int* __restrict__ gi,
                                           const float* __restrict__ p,
                                           float* __restrict__ part) {
    int chunk = blockIdx.x, dthird = blockIdx.y, b = blockIdx.z;
    int tid = threadIdx.x;
    __shared__ float acc[Ch * 256];
    for (int i = tid; i < Ch * 256; i += 256) acc[i] = 0.f;
    __syncthreads();
    int base = chunk * 1250;  // 16*1250 = 20000 exact
    int wv = tid >> 6, ln = tid & 63;
    for (int t = wv; t < 1250; t += 4) {
        int n = base + t;
        float pv = p[b * Nh + n];
        if (pv > 1e-12f) {
            int c = gi[b * Nh + n];
            const float* gr = &grid[((size_t)(b * Nh + n)) * Dh + dthird * 256];
#pragma unroll
            for (int k = 0; k < 4; ++k) {
                float v = gr[ln + k * 64];
                atomicAdd(&acc[c * 256 + ln + k * 64], pv * v);
            }
        }
    }
    __syncthreads();
    size_t po = (((size_t)(b * 3 + dthird)) * 16 + chunk) * (Ch * 256);
    for (int i = tid; i < Ch * 256; i += 256) part[po + i] = acc[i];
}

// ---------------- final: S-reduce + S@W_grid.T + candidate LN + combine ----------------
__global__ __launch_bounds__(256) void k_final(const float* __restrict__ part,
                                               const float* __restrict__ den_ws,
                                               const float* __restrict__ cands,
                                               const float* __restrict__ W_cand,
                                               const float* __restrict__ b_cand,
                                               const float* __restrict__ ln_g,
                                               const float* __restrict__ ln_b,
                                               const float* __restrict__ lang,
                                               const float* __restrict__ W_grid,
                                               const float* __restrict__ b_grid,
                                               float* __restrict__ out) {
    int b = blockIdx.x / Ch, c = blockIdx.x % Ch;
    int tid = threadIdx.x;
    __shared__ float S[Dh];
    __shared__ float cv[Dh];
    __shared__ float red[8];
    __shared__ float mu_s, rs_s;
    for (int d = tid; d < Dh; d += 256) {
        int third = d >> 8, dp = d & 255;
        float s = 0.f;
        for (int k = 0; k < 16; ++k)
            s += part[(((size_t)(b * 3 + third)) * 16 + k) * (Ch * 256) + c * 256 + dp];
        S[d] = s;
    }
    float cx = cands[(b * Ch + c) * 2 + 0], cy = cands[(b * Ch + c) * 2 + 1];
    for (int d = tid; d < Dh; d += 256)
        cv[d] = W_cand[d * 2] * cx + W_cand[d * 2 + 1] * cy + b_cand[d];
    __syncthreads();
    float ls = 0.f;
    for (int d = tid; d < Dh; d += 256) ls += cv[d];
    for (int m = 32; m; m >>= 1) ls += __shfl_xor(ls, m);
    if ((tid & 63) == 0) red[tid >> 6] = ls;
    __syncthreads();
    if (tid == 0) mu_s = (red[0] + red[1] + red[2] + red[3]) * (1.f / Dh);
    __syncthreads();
    float mu = mu_s;
    float lv = 0.f;
    for (int d = tid; d < Dh; d += 256) { float t = cv[d] - mu; lv += t * t; }
    for (int m = 32; m; m >>= 1) lv += __shfl_xor(lv, m);
    if ((tid & 63) == 0) red[4 + (tid >> 6)] = lv;
    __syncthreads();
    if (tid == 0) rs_s = rsqrtf((red[4] + red[5] + red[6] + red[7]) * (1.f / Dh) + 1e-12f);
    __syncthreads();
    float rs = rs_s;
    float den = den_ws[b * Ch + c];
#pragma unroll
    for (int j = 0; j < 3; ++j) {
        int d = tid + j * 256;
        float gm = 0.f;
        if (den > 0.f) {
            float s = 0.f;
            const float* wr = &W_grid[(size_t)d * Dh];
            for (int k = 0; k < Dh; k += 4) {
                float4 w4 = *(const float4*)&wr[k];
                float4 s4 = *(const float4*)&S[k];
                s += w4.x * s4.x + w4.y * s4.y + w4.z * s4.z + w4.w * s4.w;
            }
            gm = s + b_grid[d];
        }
        float cn = (cv[d] - mu) * rs * ln_g[d] + ln_b[d];
        out[((size_t)(b * (Fh + Ch) + Fh + c)) * Dh + d] =
            cn * lang[((size_t)b * Lh) * Dh + d] + gm;
    }
}

extern "C" void kernel_launch(void* const* d_in, const int* in_sizes, int n_in,
                              void* d_out, int out_size, void* d_ws, size_t ws_size,
                              hipStream_t stream) {
    (void)in_sizes; (void)n_in; (void)out_size; (void)ws_size;
    const float* lang      = (const float*)d_in[0];
    const float* lang_cls  = (const float*)d_in[1];
    const float* frames    = (const float*)d_in[2];
    const float* cands     = (const float*)d_in[3];
    const float* grid_fts  = (const float*)d_in[4];
    const int*   grid_idx  = (const int*)d_in[5];
    const float* W_in      = (const float*)d_in[6];
    const float* W_out     = (const float*)d_in[7];
    const float* W_fc2     = (const float*)d_in[8];
    const float* b_fc2     = (const float*)d_in[9];
    const float* W_text    = (const float*)d_in[10];
    const float* b_text    = (const float*)d_in[11];
    const float* W_grid    = (const float*)d_in[12];
    const float* b_grid    = (const float*)d_in[13];
    const float* W_cand    = (const float*)d_in[14];
    const float* b_cand    = (const float*)d_in[15];
    const float* ln_g      = (const float*)d_in[16];
    const float* ln_b      = (const float*)d_in[17];
    float* out = (float*)d_out;
    float* ws  = (float*)d_ws;

    float* text   = ws;                 // 393216
    float* tgt    = ws + 393216;        // 512 (392 used)
    float* wbuf   = ws + 393728;        // 160000
    float* pbuf   = ws + 553728;        // 160000
    float* m_ws   = ws + 713728;        // 288
    float* den_ws = ws + 714016;        // 288
    float* part   = ws + 714304;        // 8*3*16*9216 = 3538944

    hipLaunchKernelGGL(k_text,   dim3(Bh * 32), dim3(256), 0, stream, lang, W_text, b_text, text);
    hipLaunchKernelGGL(k_target, dim3(Bh), dim3(64), 0, stream, lang_cls, W_in, tgt);
    hipLaunchKernelGGL(k_frames, dim3(Bh * Fh), dim3(256), 0, stream,
                       frames, lang_cls, tgt, W_out, W_fc2, b_fc2, out);
    hipLaunchKernelGGL(k_w,      dim3((Nh + 63) / 64, Bh), dim3(256), 0, stream,
                       grid_fts, text, wbuf);
    hipLaunchKernelGGL(k_mden,   dim3(Bh), dim3(256), 0, stream, wbuf, grid_idx, m_ws, den_ws);
    hipLaunchKernelGGL(k_p,      dim3(Nh * Bh / 256), dim3(256), 0, stream,
                       wbuf, grid_idx, m_ws, den_ws, pbuf);
    hipLaunchKernelGGL(k_S,      dim3(16, 3, Bh), dim3(256), 0, stream,
                       grid_fts, grid_idx, pbuf, part);
    hipLaunchKernelGGL(k_final,  dim3(Bh * Ch), dim3(256), 0, stream,
                       part, den_ws, cands, W_cand, b_cand, ln_g, ln_b, lang, W_grid, b_grid, out);
}

// Round 2
// 540.969 us; speedup vs baseline: 1.8358x; 1.8358x over previous
//
#include <hip/hip_runtime.h>
#include <math.h>

#define Bh 8
#define Lh 64
#define Dh 768
#define Fh 50
#define Ph 49
#define Ah 49
#define Nh 20000
#define Ch 36
#define CAP 2048
#define CUT 1e-7f

__device__ __forceinline__ float dec_max(unsigned u) {
    if (u == 0u) return 0.f;
    return (u & 0x80000000u) ? __uint_as_float(u ^ 0x80000000u) : __uint_as_float(~u);
}

// ---------------- zero small accumulators ----------------
__global__ void k_zero(unsigned* __restrict__ m_u, float* __restrict__ den,
                       int* __restrict__ cnt) {
    int i = blockIdx.x * 256 + threadIdx.x;
    if (i < Bh * Ch) { m_u[i] = 0u; den[i] = 0.f; cnt[i] = 0; }
}

// ---------------- text = lang @ W_text.T + b_text ----------------
__global__ __launch_bounds__(256) void k_text(const float* __restrict__ lang,
                                              const float* __restrict__ Wt,
                                              const float* __restrict__ bt,
                                              float* __restrict__ text) {
    int b  = blockIdx.x >> 5;
    int l0 = (blockIdx.x & 31) * 2;
    int tid = threadIdx.x;
    __shared__ float ls[2][Dh];
    for (int i = tid; i < 2 * Dh; i += 256)
        ls[i / Dh][i % Dh] = lang[((size_t)(b * Lh + l0 + i / Dh)) * Dh + (i % Dh)];
    __syncthreads();
    float acc[2][3] = {{0.f, 0.f, 0.f}, {0.f, 0.f, 0.f}};
    for (int k = 0; k < Dh; k += 4) {
        float4 v0 = *(const float4*)&ls[0][k];
        float4 v1 = *(const float4*)&ls[1][k];
#pragma unroll
        for (int j = 0; j < 3; ++j) {
            int d = tid + j * 256;
            float4 wv = *(const float4*)&Wt[(size_t)d * Dh + k];
            acc[0][j] += wv.x * v0.x + wv.y * v0.y + wv.z * v0.z + wv.w * v0.w;
            acc[1][j] += wv.x * v1.x + wv.y * v1.y + wv.z * v1.z + wv.w * v1.w;
        }
    }
#pragma unroll
    for (int li = 0; li < 2; ++li)
#pragma unroll
        for (int j = 0; j < 3; ++j) {
            int d = tid + j * 256;
            text[((size_t)(b * Lh + l0 + li)) * Dh + d] = acc[li][j] + bt[d];
        }
}

// ---------------- target = lang_cls @ W_in.T ----------------
__global__ void k_target(const float* __restrict__ lang_cls, const float* __restrict__ W_in,
                         float* __restrict__ tgt) {
    int b = blockIdx.x, a = threadIdx.x;
    if (a < Ah) {
        float s = 0.f;
        for (int k = 0; k < Ah; ++k) s += lang_cls[b * Ah + k] * W_in[a * Ah + k];
        tgt[b * Ah + a] = s;
    }
}

// ---------------- frames attention path -> out[b, 0..F) ----------------
__global__ __launch_bounds__(256) void k_frames(const float* __restrict__ frames,
                                                const float* __restrict__ lang_cls,
                                                const float* __restrict__ tgt_ws,
                                                const float* __restrict__ W_out,
                                                const float* __restrict__ W_fc2,
                                                const float* __restrict__ b_fc2,
                                                float* __restrict__ out) {
    int b = blockIdx.x / Fh, f = blockIdx.x % Fh;
    int tid = threadIdx.x;
    __shared__ float fr[Ph * Ah];
    __shared__ float tg[Ah], cl[Ah], at[Ph], wc[Ah], af[Ah];
    const float* fp = frames + ((size_t)(b * Fh + f)) * (Ph * Ah);
    for (int i = tid; i < Ph * Ah; i += 256) fr[i] = fp[i];
    if (tid < Ah) { tg[tid] = tgt_ws[b * Ah + tid]; cl[tid] = lang_cls[b * Ah + tid]; }
    __syncthreads();
    if (tid < Ph) {
        float s = 0.f;
        for (int a = 0; a < Ah; ++a) s += fr[tid * Ah + a] * tg[a];
        at[tid] = s;
    }
    __syncthreads();
    if (tid < 64) {
        float raw = (tid < Ph) ? at[tid] : -3.4e38f;
        float v = raw;
        for (int m = 32; m; m >>= 1) v = fmaxf(v, __shfl_xor(v, m));
        float e = (tid < Ph) ? expf(raw - v) : 0.f;
        float s = e;
        for (int m = 32; m; m >>= 1) s += __shfl_xor(s, m);
        if (tid < Ph) at[tid] = e / s;
    }
    __syncthreads();
    if (tid < Ah) {
        float s = 0.f;
        for (int p = 0; p < Ph; ++p) s += at[p] * fr[p * Ah + tid];
        wc[tid] = s;
    }
    __syncthreads();
    if (tid < Ah) {
        float s = 0.f;
        for (int a = 0; a < Ah; ++a)
            s += wc[a] * W_out[tid * (2 * Ah) + a] + cl[a] * W_out[tid * (2 * Ah) + Ah + a];
        af[tid] = tanhf(s);
    }
    __syncthreads();
    for (int d = tid; d < Dh; d += 256) {
        float s = b_fc2[d];
        for (int j = 0; j < Ah; ++j) s += af[j] * W_fc2[d * Ah + j];
        out[((size_t)(b * (Fh + Ch) + f)) * Dh + d] = s;
    }
}

// ---------------- w[b,n] = max_l dot(grid_fts[b,n], text[b,l]) ----------------
__global__ __launch_bounds__(256) void k_w(const float* __restrict__ grid,
                                           const float* __restrict__ text,
                                           float* __restrict__ w) {
    __shared__ float As[64][68];
    __shared__ float Bs[64][68];
    int b = blockIdx.y;
    int n0 = blockIdx.x * 64;
    int tid = threadIdx.x;
    int tp = tid >> 4, tl = tid & 15;
    float c[4][4] = {};
    const float* tb = text + (size_t)b * Lh * Dh;
    for (int kt = 0; kt < Dh; kt += 64) {
#pragma unroll
        for (int r = 0; r < 4; ++r) {
            int pt = tp + 16 * r;
            int n = n0 + pt; if (n >= Nh) n = Nh - 1;
            float4 av = *(const float4*)&grid[((size_t)(b * Nh + n)) * Dh + kt + tl * 4];
            As[tl * 4 + 0][pt] = av.x; As[tl * 4 + 1][pt] = av.y;
            As[tl * 4 + 2][pt] = av.z; As[tl * 4 + 3][pt] = av.w;
            float4 bv = *(const float4*)&tb[(size_t)pt * Dh + kt + tl * 4];
            Bs[tl * 4 + 0][pt] = bv.x; Bs[tl * 4 + 1][pt] = bv.y;
            Bs[tl * 4 + 2][pt] = bv.z; Bs[tl * 4 + 3][pt] = bv.w;
        }
        __syncthreads();
#pragma unroll 8
        for (int k = 0; k < 64; ++k) {
            float4 a  = *(const float4*)&As[k][tp << 2];
            float4 bb = *(const float4*)&Bs[k][tl << 2];
            c[0][0] += a.x * bb.x; c[0][1] += a.x * bb.y; c[0][2] += a.x * bb.z; c[0][3] += a.x * bb.w;
            c[1][0] += a.y * bb.x; c[1][1] += a.y * bb.y; c[1][2] += a.y * bb.z; c[1][3] += a.y * bb.w;
            c[2][0] += a.z * bb.x; c[2][1] += a.z * bb.y; c[2][2] += a.z * bb.z; c[2][3] += a.z * bb.w;
            c[3][0] += a.w * bb.x; c[3][1] += a.w * bb.y; c[3][2] += a.w * bb.z; c[3][3] += a.w * bb.w;
        }
        __syncthreads();
    }
#pragma unroll
    for (int i = 0; i < 4; ++i) {
        float v = fmaxf(fmaxf(c[i][0], c[i][1]), fmaxf(c[i][2], c[i][3]));
        v = fmaxf(v, __shfl_xor(v, 1));
        v = fmaxf(v, __shfl_xor(v, 2));
        v = fmaxf(v, __shfl_xor(v, 4));
        v = fmaxf(v, __shfl_xor(v, 8));
        int n = n0 + tp * 4 + i;
        if (tl == 0 && n < Nh) w[b * Nh + n] = v;
    }
}

// ---------------- per-cell max (pass 1) ----------------
__global__ __launch_bounds__(256) void k_max(const float* __restrict__ w,
                                             const int* __restrict__ gi,
                                             unsigned* __restrict__ m_u) {
    int b = blockIdx.y;
    int n = blockIdx.x * 256 + threadIdx.x;
    __shared__ unsigned mu[Ch];
    if (threadIdx.x < Ch) mu[threadIdx.x] = 0u;
    __syncthreads();
    if (n < Nh) {
        float v = w[b * Nh + n];
        unsigned u = __float_as_uint(v);
        u = (u & 0x80000000u) ? ~u : (u | 0x80000000u);
        atomicMax(&mu[gi[b * Nh + n]], u);
    }
    __syncthreads();
    if (threadIdx.x < Ch && mu[threadIdx.x])
        atomicMax(&m_u[b * Ch + threadIdx.x], mu[threadIdx.x]);
}

// ---------------- per-cell exp-sum (pass 2) ----------------
__global__ __launch_bounds__(256) void k_den(const float* __restrict__ w,
                                             const int* __restrict__ gi,
                                             const unsigned* __restrict__ m_u,
                                             float* __restrict__ den) {
    int b = blockIdx.y;
    int n = blockIdx.x * 256 + threadIdx.x;
    __shared__ float dn[Ch];
    if (threadIdx.x < Ch) dn[threadIdx.x] = 0.f;
    __syncthreads();
    if (n < Nh) {
        int c = gi[b * Nh + n];
        float m = dec_max(m_u[b * Ch + c]);
        atomicAdd(&dn[c], expf(w[b * Nh + n] - m));
    }
    __syncthreads();
    if (threadIdx.x < Ch && dn[threadIdx.x] != 0.f)
        atomicAdd(&den[b * Ch + threadIdx.x], dn[threadIdx.x]);
}

// ---------------- p + compaction into per-(b,c) buckets ----------------
__global__ __launch_bounds__(256) void k_pc(const float* __restrict__ w,
                                            const int* __restrict__ gi,
                                            const unsigned* __restrict__ m_u,
                                            const float* __restrict__ den,
                                            int* __restrict__ cnt,
                                            int* __restrict__ bn,
                                            float* __restrict__ bp) {
    int b = blockIdx.y;
    int n = blockIdx.x * 256 + threadIdx.x;
    if (n >= Nh) return;
    int c = gi[b * Nh + n];
    float dv = den[b * Ch + c];
    if (dv <= 0.f) return;
    float pv = expf(w[b * Nh + n] - dec_max(m_u[b * Ch + c])) / dv;
    if (pv > CUT) {
        int pos = atomicAdd(&cnt[b * Ch + c], 1);
        if (pos < CAP) {
            bn[(b * Ch + c) * CAP + pos] = n;
            bp[(b * Ch + c) * CAP + pos] = pv;
        }
    }
}

// ---------------- S[b][c][d] = sum over bucket of p * grid[n][d] ----------------
// grid (36 c, 3 dq, 8 b); threads span 256 consecutive d -> coalesced row slices.
__global__ __launch_bounds__(256) void k_S3(const float* __restrict__ grid,
                                            const int* __restrict__ cnt,
                                            const int* __restrict__ bn,
                                            const float* __restrict__ bp,
                                            float* __restrict__ S) {
    int c = blockIdx.x, dq = blockIdx.y, b = blockIdx.z;
    int d = dq * 256 + threadIdx.x;
    int len = cnt[b * Ch + c]; if (len > CAP) len = CAP;
    size_t base = (size_t)(b * Ch + c) * CAP;
    const float* gb = grid + (size_t)b * Nh * Dh + d;
    float a0 = 0.f, a1 = 0.f, a2 = 0.f, a3 = 0.f;
    int i = 0;
    for (; i + 4 <= len; i += 4) {
        int   n0 = bn[base + i],     n1 = bn[base + i + 1];
        int   n2 = bn[base + i + 2], n3 = bn[base + i + 3];
        float p0 = bp[base + i],     p1 = bp[base + i + 1];
        float p2 = bp[base + i + 2], p3 = bp[base + i + 3];
        a0 += p0 * gb[(size_t)n0 * Dh];
        a1 += p1 * gb[(size_t)n1 * Dh];
        a2 += p2 * gb[(size_t)n2 * Dh];
        a3 += p3 * gb[(size_t)n3 * Dh];
    }
    for (; i < len; ++i)
        a0 += bp[base + i] * gb[(size_t)bn[base + i] * Dh];
    S[(size_t)(b * Ch + c) * Dh + d] = (a0 + a1) + (a2 + a3);
}

// ---------------- G = S @ W_grid.T + b_grid ----------------
// grid (108, 8): cq = bx/12 (4 cells), dt = bx%12 (64 d). Wave-uniform S rows.
__global__ __launch_bounds__(256) void k_gg(const float* __restrict__ S,
                                            const float* __restrict__ Wg,
                                            const float* __restrict__ bg,
                                            float* __restrict__ G) {
    int b = blockIdx.y;
    int cq = blockIdx.x / 12, dt = blockIdx.x % 12;
    int c = cq * 4 + (threadIdx.x >> 6);
    int d = dt * 64 + (threadIdx.x & 63);
    const float* sr = S + (size_t)(b * Ch + c) * Dh;
    const float* wr = Wg + (size_t)d * Dh;
    float acc = 0.f;
    for (int k = 0; k < Dh; k += 4) {
        float4 s4 = *(const float4*)&sr[k];
        float4 w4 = *(const float4*)&wr[k];
        acc += s4.x * w4.x + s4.y * w4.y + s4.z * w4.z + s4.w * w4.w;
    }
    G[(size_t)(b * Ch + c) * Dh + d] = acc + bg[d];
}

// ---------------- final: candidate LN + combine ----------------
__global__ __launch_bounds__(256) void k_final(const float* __restrict__ G,
                                               const float* __restrict__ den,
                                               const float* __restrict__ cands,
                                               const float* __restrict__ W_cand,
                                               const float* __restrict__ b_cand,
                                               const float* __restrict__ ln_g,
                                               const float* __restrict__ ln_b,
                                               const float* __restrict__ lang,
                                               float* __restrict__ out) {
    int b = blockIdx.x / Ch, c = blockIdx.x % Ch;
    int tid = threadIdx.x;
    __shared__ float cv[Dh];
    __shared__ float red[8];
    __shared__ float mu_s, rs_s;
    float cx = cands[(b * Ch + c) * 2 + 0], cy = cands[(b * Ch + c) * 2 + 1];
    for (int d = tid; d < Dh; d += 256)
        cv[d] = W_cand[d * 2] * cx + W_cand[d * 2 + 1] * cy + b_cand[d];
    __syncthreads();
    float ls = 0.f;
    for (int d = tid; d < Dh; d += 256) ls += cv[d];
    for (int m = 32; m; m >>= 1) ls += __shfl_xor(ls, m);
    if ((tid & 63) == 0) red[tid >> 6] = ls;
    __syncthreads();
    if (tid == 0) mu_s = (red[0] + red[1] + red[2] + red[3]) * (1.f / Dh);
    __syncthreads();
    float mu = mu_s;
    float lv = 0.f;
    for (int d = tid; d < Dh; d += 256) { float t = cv[d] - mu; lv += t * t; }
    for (int m = 32; m; m >>= 1) lv += __shfl_xor(lv, m);
    if ((tid & 63) == 0) red[4 + (tid >> 6)] = lv;
    __syncthreads();
    if (tid == 0) rs_s = rsqrtf((red[4] + red[5] + red[6] + red[7]) * (1.f / Dh) + 1e-12f);
    __syncthreads();
    float rs = rs_s;
    float dv = den[b * Ch + c];
#pragma unroll
    for (int j = 0; j < 3; ++j) {
        int d = tid + j * 256;
        float gm = (dv > 0.f) ? G[(size_t)(b * Ch + c) * Dh + d] : 0.f;
        float cn = (cv[d] - mu) * rs * ln_g[d] + ln_b[d];
        out[((size_t)(b * (Fh + Ch) + Fh + c)) * Dh + d] =
            cn * lang[((size_t)b * Lh) * Dh + d] + gm;
    }
}

extern "C" void kernel_launch(void* const* d_in, const int* in_sizes, int n_in,
                              void* d_out, int out_size, void* d_ws, size_t ws_size,
                              hipStream_t stream) {
    (void)in_sizes; (void)n_in; (void)out_size; (void)ws_size;
    const float* lang      = (const float*)d_in[0];
    const float* lang_cls  = (const float*)d_in[1];
    const float* frames    = (const float*)d_in[2];
    const float* cands     = (const float*)d_in[3];
    const float* grid_fts  = (const float*)d_in[4];
    const int*   grid_idx  = (const int*)d_in[5];
    const float* W_in      = (const float*)d_in[6];
    const float* W_out     = (const float*)d_in[7];
    const float* W_fc2     = (const float*)d_in[8];
    const float* b_fc2     = (const float*)d_in[9];
    const float* W_text    = (const float*)d_in[10];
    const float* b_text    = (const float*)d_in[11];
    const float* W_grid    = (const float*)d_in[12];
    const float* b_grid    = (const float*)d_in[13];
    const float* W_cand    = (const float*)d_in[14];
    const float* b_cand    = (const float*)d_in[15];
    const float* ln_g      = (const float*)d_in[16];
    const float* ln_b      = (const float*)d_in[17];
    float* out = (float*)d_out;
    float* ws  = (float*)d_ws;

    float*    text = ws;                       // 393216
    float*    tgt  = ws + 393216;              // 512
    float*    wbuf = ws + 393728;              // 160000
    unsigned* m_u  = (unsigned*)(ws + 553728); // 288
    float*    den  = ws + 554016;              // 288
    int*      cnt  = (int*)(ws + 554304);      // 288
    int*      bn   = (int*)(ws + 554592);      // 589824
    float*    bp   = ws + 1144416;             // 589824
    float*    S    = ws + 1734240;             // 221184
    float*    G    = ws + 1955424;             // 221184

    hipLaunchKernelGGL(k_zero,   dim3(2), dim3(256), 0, stream, m_u, den, cnt);
    hipLaunchKernelGGL(k_text,   dim3(Bh * 32), dim3(256), 0, stream, lang, W_text, b_text, text);
    hipLaunchKernelGGL(k_target, dim3(Bh), dim3(64), 0, stream, lang_cls, W_in, tgt);
    hipLaunchKernelGGL(k_frames, dim3(Bh * Fh), dim3(256), 0, stream,
                       frames, lang_cls, tgt, W_out, W_fc2, b_fc2, out);
    hipLaunchKernelGGL(k_w,      dim3((Nh + 63) / 64, Bh), dim3(256), 0, stream,
                       grid_fts, text, wbuf);
    hipLaunchKernelGGL(k_max,    dim3(79, Bh), dim3(256), 0, stream, wbuf, grid_idx, m_u);
    hipLaunchKernelGGL(k_den,    dim3(79, Bh), dim3(256), 0, stream, wbuf, grid_idx, m_u, den);
    hipLaunchKernelGGL(k_pc,     dim3(79, Bh), dim3(256), 0, stream,
                       wbuf, grid_idx, m_u, den, cnt, bn, bp);
    hipLaunchKernelGGL(k_S3,     dim3(Ch, 3, Bh), dim3(256), 0, stream,
                       grid_fts, cnt, bn, bp, S);
    hipLaunchKernelGGL(k_gg,     dim3(108, Bh), dim3(256), 0, stream, S, W_grid, b_grid, G);
    hipLaunchKernelGGL(k_final,  dim3(Bh * Ch), dim3(256), 0, stream,
                       G, den, cands, W_cand, b_cand, ln_g, ln_b, lang, out);
}

// Round 3
// 421.025 us; speedup vs baseline: 2.3588x; 1.2849x over previous
//
#include <hip/hip_runtime.h>
#include <math.h>

#define Bh 8
#define Lh 64
#define Dh 768
#define Fh 50
#define Ph 49
#define Ah 49
#define Nh 20000
#define Ch 36
#define CAP 2048
#define CUT 1e-7f

typedef __bf16 bf16x8 __attribute__((ext_vector_type(8)));
typedef float f32x4 __attribute__((ext_vector_type(4)));
union U { uint4 u; bf16x8 v; };

__device__ __forceinline__ void cvt2(float a0, float a1, unsigned& h, unsigned& l) {
    unsigned u0 = __float_as_uint(a0), u1 = __float_as_uint(a1);
    unsigned h0 = u0 & 0xFFFF0000u, h1 = u1 & 0xFFFF0000u;
    h = (h0 >> 16) | h1;
    float l0 = a0 - __uint_as_float(h0);
    float l1 = a1 - __uint_as_float(h1);
    l = (__float_as_uint(l0) >> 16) | (__float_as_uint(l1) & 0xFFFF0000u);
}

__device__ __forceinline__ void cvt8(float4 p, float4 q, bf16x8& h8, bf16x8& l8) {
    U h, l;
    cvt2(p.x, p.y, h.u.x, l.u.x);
    cvt2(p.z, p.w, h.u.y, l.u.y);
    cvt2(q.x, q.y, h.u.z, l.u.z);
    cvt2(q.z, q.w, h.u.w, l.u.w);
    h8 = h.v; l8 = l.v;
}

__device__ __forceinline__ float dec_max(unsigned u) {
    if (u == 0u) return 0.f;
    return (u & 0x80000000u) ? __uint_as_float(u ^ 0x80000000u) : __uint_as_float(~u);
}

// ---------------- zero small accumulators ----------------
__global__ void k_zero(unsigned* __restrict__ m_u, float* __restrict__ den,
                       int* __restrict__ cnt) {
    int i = blockIdx.x * 256 + threadIdx.x;
    if (i < Bh * Ch) { m_u[i] = 0u; den[i] = 0.f; cnt[i] = 0; }
}

// ---------------- text = lang @ W_text.T + b_text ----------------
__global__ __launch_bounds__(256) void k_text(const float* __restrict__ lang,
                                              const float* __restrict__ Wt,
                                              const float* __restrict__ bt,
                                              float* __restrict__ text) {
    int b  = blockIdx.x >> 5;
    int l0 = (blockIdx.x & 31) * 2;
    int tid = threadIdx.x;
    __shared__ float ls[2][Dh];
    for (int i = tid; i < 2 * Dh; i += 256)
        ls[i / Dh][i % Dh] = lang[((size_t)(b * Lh + l0 + i / Dh)) * Dh + (i % Dh)];
    __syncthreads();
    float acc[2][3] = {{0.f, 0.f, 0.f}, {0.f, 0.f, 0.f}};
    for (int k = 0; k < Dh; k += 4) {
        float4 v0 = *(const float4*)&ls[0][k];
        float4 v1 = *(const float4*)&ls[1][k];
#pragma unroll
        for (int j = 0; j < 3; ++j) {
            int d = tid + j * 256;
            float4 wv = *(const float4*)&Wt[(size_t)d * Dh + k];
            acc[0][j] += wv.x * v0.x + wv.y * v0.y + wv.z * v0.z + wv.w * v0.w;
            acc[1][j] += wv.x * v1.x + wv.y * v1.y + wv.z * v1.z + wv.w * v1.w;
        }
    }
#pragma unroll
    for (int li = 0; li < 2; ++li)
#pragma unroll
        for (int j = 0; j < 3; ++j) {
            int d = tid + j * 256;
            text[((size_t)(b * Lh + l0 + li)) * Dh + d] = acc[li][j] + bt[d];
        }
}

// ---------------- text -> fragment-major bf16 hi/lo ----------------
// layout: [b][ks(24)][ct(4)][lane(64)][8 bf16]; lane holds B[col=ct*16+(l&15)][k=ks*32+(l>>4)*8 + 0..7]
__global__ __launch_bounds__(256) void k_tfrag(const float* __restrict__ text,
                                               uint4* __restrict__ textH,
                                               uint4* __restrict__ textL) {
    int gid = blockIdx.x * 256 + threadIdx.x;  // 192*256 = 49152 exact
    int l  = gid & 63;
    int ct = (gid >> 6) & 3;
    int bk = gid >> 8;             // b*24 + ks
    int b  = bk / 24, ks = bk % 24;
    const float* src = text + ((size_t)(b * Lh + ct * 16 + (l & 15))) * Dh
                     + ks * 32 + (l >> 4) * 8;
    float4 p = *(const float4*)src;
    float4 q = *(const float4*)(src + 4);
    U h, lo;
    cvt2(p.x, p.y, h.u.x, lo.u.x);
    cvt2(p.z, p.w, h.u.y, lo.u.y);
    cvt2(q.x, q.y, h.u.z, lo.u.z);
    cvt2(q.z, q.w, h.u.w, lo.u.w);
    textH[gid] = h.u;
    textL[gid] = lo.u;
}

// ---------------- target = lang_cls @ W_in.T ----------------
__global__ void k_target(const float* __restrict__ lang_cls, const float* __restrict__ W_in,
                         float* __restrict__ tgt) {
    int b = blockIdx.x, a = threadIdx.x;
    if (a < Ah) {
        float s = 0.f;
        for (int k = 0; k < Ah; ++k) s += lang_cls[b * Ah + k] * W_in[a * Ah + k];
        tgt[b * Ah + a] = s;
    }
}

// ---------------- frames attention path -> out[b, 0..F) ----------------
__global__ __launch_bounds__(256) void k_frames(const float* __restrict__ frames,
                                                const float* __restrict__ lang_cls,
                                                const float* __restrict__ tgt_ws,
                                                const float* __restrict__ W_out,
                                                const float* __restrict__ W_fc2,
                                                const float* __restrict__ b_fc2,
                                                float* __restrict__ out) {
    int b = blockIdx.x / Fh, f = blockIdx.x % Fh;
    int tid = threadIdx.x;
    __shared__ float fr[Ph * Ah];
    __shared__ float tg[Ah], cl[Ah], at[Ph], wc[Ah], af[Ah];
    const float* fp = frames + ((size_t)(b * Fh + f)) * (Ph * Ah);
    for (int i = tid; i < Ph * Ah; i += 256) fr[i] = fp[i];
    if (tid < Ah) { tg[tid] = tgt_ws[b * Ah + tid]; cl[tid] = lang_cls[b * Ah + tid]; }
    __syncthreads();
    if (tid < Ph) {
        float s = 0.f;
        for (int a = 0; a < Ah; ++a) s += fr[tid * Ah + a] * tg[a];
        at[tid] = s;
    }
    __syncthreads();
    if (tid < 64) {
        float raw = (tid < Ph) ? at[tid] : -3.4e38f;
        float v = raw;
        for (int m = 32; m; m >>= 1) v = fmaxf(v, __shfl_xor(v, m));
        float e = (tid < Ph) ? expf(raw - v) : 0.f;
        float s = e;
        for (int m = 32; m; m >>= 1) s += __shfl_xor(s, m);
        if (tid < Ph) at[tid] = e / s;
    }
    __syncthreads();
    if (tid < Ah) {
        float s = 0.f;
        for (int p = 0; p < Ph; ++p) s += at[p] * fr[p * Ah + tid];
        wc[tid] = s;
    }
    __syncthreads();
    if (tid < Ah) {
        float s = 0.f;
        for (int a = 0; a < Ah; ++a)
            s += wc[a] * W_out[tid * (2 * Ah) + a] + cl[a] * W_out[tid * (2 * Ah) + Ah + a];
        af[tid] = tanhf(s);
    }
    __syncthreads();
    for (int d = tid; d < Dh; d += 256) {
        float s = b_fc2[d];
        for (int j = 0; j < Ah; ++j) s += af[j] * W_fc2[d * Ah + j];
        out[((size_t)(b * (Fh + Ch) + f)) * Dh + d] = s;
    }
}

// ---------------- w[b,n] via split-bf16 MFMA, no LDS ----------------
// block = 4 waves; wave = 32 rows x 64 cols; A frags loaded by consumer lanes.
__global__ __launch_bounds__(256) void k_w(const float* __restrict__ grid,
                                           const uint4* __restrict__ textH,
                                           const uint4* __restrict__ textL,
                                           float* __restrict__ w) {
    int b = blockIdx.y;
    int tid = threadIdx.x;
    int wv = tid >> 6, l = tid & 63;
    int nb = blockIdx.x * 128 + wv * 32;
    int r0 = nb + (l & 15);
    int r1 = r0 + 16;
    int r0c = r0 < Nh ? r0 : Nh - 1;
    int r1c = r1 < Nh ? r1 : Nh - 1;
    const float4* pa0 = (const float4*)(grid + ((size_t)b * Nh + r0c) * Dh) + ((l >> 4) * 2);
    const float4* pa1 = (const float4*)(grid + ((size_t)b * Nh + r1c) * Dh) + ((l >> 4) * 2);
    const uint4* pbh = textH + ((size_t)b * 24 * 4 * 64) + l;
    const uint4* pbl = textL + ((size_t)b * 24 * 4 * 64) + l;

    f32x4 acc[2][4];
#pragma unroll
    for (int i = 0; i < 2; ++i)
#pragma unroll
        for (int j = 0; j < 4; ++j) acc[i][j] = (f32x4){0.f, 0.f, 0.f, 0.f};

    for (int ks = 0; ks < 24; ++ks) {
        float4 x00 = pa0[ks * 8], x01 = pa0[ks * 8 + 1];
        float4 x10 = pa1[ks * 8], x11 = pa1[ks * 8 + 1];
        uint4 bhu0 = pbh[ks * 256 +   0], bhu1 = pbh[ks * 256 +  64];
        uint4 bhu2 = pbh[ks * 256 + 128], bhu3 = pbh[ks * 256 + 192];
        uint4 blu0 = pbl[ks * 256 +   0], blu1 = pbl[ks * 256 +  64];
        uint4 blu2 = pbl[ks * 256 + 128], blu3 = pbl[ks * 256 + 192];
        bf16x8 ah0, al0, ah1, al1;
        cvt8(x00, x01, ah0, al0);
        cvt8(x10, x11, ah1, al1);
        uint4 bhu[4] = {bhu0, bhu1, bhu2, bhu3};
        uint4 blu[4] = {blu0, blu1, blu2, blu3};
#pragma unroll
        for (int ct = 0; ct < 4; ++ct) {
            U ubh, ubl; ubh.u = bhu[ct]; ubl.u = blu[ct];
            bf16x8 bh = ubh.v, bl = ubl.v;
            acc[0][ct] = __builtin_amdgcn_mfma_f32_16x16x32_bf16(ah0, bh, acc[0][ct], 0, 0, 0);
            acc[0][ct] = __builtin_amdgcn_mfma_f32_16x16x32_bf16(al0, bh, acc[0][ct], 0, 0, 0);
            acc[0][ct] = __builtin_amdgcn_mfma_f32_16x16x32_bf16(ah0, bl, acc[0][ct], 0, 0, 0);
            acc[1][ct] = __builtin_amdgcn_mfma_f32_16x16x32_bf16(ah1, bh, acc[1][ct], 0, 0, 0);
            acc[1][ct] = __builtin_amdgcn_mfma_f32_16x16x32_bf16(al1, bh, acc[1][ct], 0, 0, 0);
            acc[1][ct] = __builtin_amdgcn_mfma_f32_16x16x32_bf16(ah1, bl, acc[1][ct], 0, 0, 0);
        }
    }

    // row-max: C row = (l>>4)*4 + r (tile rt), col = ct*16 + (l&15)
#pragma unroll
    for (int rt = 0; rt < 2; ++rt) {
        float m[4];
#pragma unroll
        for (int r = 0; r < 4; ++r) {
            m[r] = fmaxf(fmaxf(acc[rt][0][r], acc[rt][1][r]),
                         fmaxf(acc[rt][2][r], acc[rt][3][r]));
            m[r] = fmaxf(m[r], __shfl_xor(m[r], 1));
            m[r] = fmaxf(m[r], __shfl_xor(m[r], 2));
            m[r] = fmaxf(m[r], __shfl_xor(m[r], 4));
            m[r] = fmaxf(m[r], __shfl_xor(m[r], 8));
        }
        if ((l & 15) == 0) {
#pragma unroll
            for (int r = 0; r < 4; ++r) {
                int row = nb + rt * 16 + (l >> 4) * 4 + r;
                if (row < Nh) w[b * Nh + row] = m[r];
            }
        }
    }
}

// ---------------- per-cell max (pass 1) ----------------
__global__ __launch_bounds__(256) void k_max(const float* __restrict__ w,
                                             const int* __restrict__ gi,
                                             unsigned* __restrict__ m_u) {
    int b = blockIdx.y;
    int n = blockIdx.x * 256 + threadIdx.x;
    __shared__ unsigned mu[Ch];
    if (threadIdx.x < Ch) mu[threadIdx.x] = 0u;
    __syncthreads();
    if (n < Nh) {
        float v = w[b * Nh + n];
        unsigned u = __float_as_uint(v);
        u = (u & 0x80000000u) ? ~u : (u | 0x80000000u);
        atomicMax(&mu[gi[b * Nh + n]], u);
    }
    __syncthreads();
    if (threadIdx.x < Ch && mu[threadIdx.x])
        atomicMax(&m_u[b * Ch + threadIdx.x], mu[threadIdx.x]);
}

// ---------------- per-cell exp-sum (pass 2) ----------------
__global__ __launch_bounds__(256) void k_den(const float* __restrict__ w,
                                             const int* __restrict__ gi,
                                             const unsigned* __restrict__ m_u,
                                             float* __restrict__ den) {
    int b = blockIdx.y;
    int n = blockIdx.x * 256 + threadIdx.x;
    __shared__ float dn[Ch];
    if (threadIdx.x < Ch) dn[threadIdx.x] = 0.f;
    __syncthreads();
    if (n < Nh) {
        int c = gi[b * Nh + n];
        float m = dec_max(m_u[b * Ch + c]);
        atomicAdd(&dn[c], expf(w[b * Nh + n] - m));
    }
    __syncthreads();
    if (threadIdx.x < Ch && dn[threadIdx.x] != 0.f)
        atomicAdd(&den[b * Ch + threadIdx.x], dn[threadIdx.x]);
}

// ---------------- p + compaction into per-(b,c) buckets ----------------
__global__ __launch_bounds__(256) void k_pc(const float* __restrict__ w,
                                            const int* __restrict__ gi,
                                            const unsigned* __restrict__ m_u,
                                            const float* __restrict__ den,
                                            int* __restrict__ cnt,
                                            int* __restrict__ bn,
                                            float* __restrict__ bp) {
    int b = blockIdx.y;
    int n = blockIdx.x * 256 + threadIdx.x;
    if (n >= Nh) return;
    int c = gi[b * Nh + n];
    float dv = den[b * Ch + c];
    if (dv <= 0.f) return;
    float pv = expf(w[b * Nh + n] - dec_max(m_u[b * Ch + c])) / dv;
    if (pv > CUT) {
        int pos = atomicAdd(&cnt[b * Ch + c], 1);
        if (pos < CAP) {
            bn[(b * Ch + c) * CAP + pos] = n;
            bp[(b * Ch + c) * CAP + pos] = pv;
        }
    }
}

// ---------------- S[b][c][d] = sum over bucket of p * grid[n][d] ----------------
__global__ __launch_bounds__(256) void k_S3(const float* __restrict__ grid,
                                            const int* __restrict__ cnt,
                                            const int* __restrict__ bn,
                                            const float* __restrict__ bp,
                                            float* __restrict__ S) {
    int c = blockIdx.x, dq = blockIdx.y, b = blockIdx.z;
    int d = dq * 256 + threadIdx.x;
    int len = cnt[b * Ch + c]; if (len > CAP) len = CAP;
    size_t base = (size_t)(b * Ch + c) * CAP;
    const float* gb = grid + (size_t)b * Nh * Dh + d;
    float a0 = 0.f, a1 = 0.f, a2 = 0.f, a3 = 0.f;
    int i = 0;
    for (; i + 4 <= len; i += 4) {
        int   n0 = bn[base + i],     n1 = bn[base + i + 1];
        int   n2 = bn[base + i + 2], n3 = bn[base + i + 3];
        float p0 = bp[base + i],     p1 = bp[base + i + 1];
        float p2 = bp[base + i + 2], p3 = bp[base + i + 3];
        a0 += p0 * gb[(size_t)n0 * Dh];
        a1 += p1 * gb[(size_t)n1 * Dh];
        a2 += p2 * gb[(size_t)n2 * Dh];
        a3 += p3 * gb[(size_t)n3 * Dh];
    }
    for (; i < len; ++i)
        a0 += bp[base + i] * gb[(size_t)bn[base + i] * Dh];
    S[(size_t)(b * Ch + c) * Dh + d] = (a0 + a1) + (a2 + a3);
}

// ---------------- G = S @ W_grid.T + b_grid ----------------
__global__ __launch_bounds__(256) void k_gg(const float* __restrict__ S,
                                            const float* __restrict__ Wg,
                                            const float* __restrict__ bg,
                                            float* __restrict__ G) {
    int b = blockIdx.y;
    int cq = blockIdx.x / 12, dt = blockIdx.x % 12;
    int c = cq * 4 + (threadIdx.x >> 6);
    int d = dt * 64 + (threadIdx.x & 63);
    const float* sr = S + (size_t)(b * Ch + c) * Dh;
    const float* wr = Wg + (size_t)d * Dh;
    float acc = 0.f;
    for (int k = 0; k < Dh; k += 4) {
        float4 s4 = *(const float4*)&sr[k];
        float4 w4 = *(const float4*)&wr[k];
        acc += s4.x * w4.x + s4.y * w4.y + s4.z * w4.z + s4.w * w4.w;
    }
    G[(size_t)(b * Ch + c) * Dh + d] = acc + bg[d];
}

// ---------------- final: candidate LN + combine ----------------
__global__ __launch_bounds__(256) void k_final(const float* __restrict__ G,
                                               const float* __restrict__ den,
                                               const float* __restrict__ cands,
                                               const float* __restrict__ W_cand,
                                               const float* __restrict__ b_cand,
                                               const float* __restrict__ ln_g,
                                               const float* __restrict__ ln_b,
                                               const float* __restrict__ lang,
                                               float* __restrict__ out) {
    int b = blockIdx.x / Ch, c = blockIdx.x % Ch;
    int tid = threadIdx.x;
    __shared__ float cv[Dh];
    __shared__ float red[8];
    __shared__ float mu_s, rs_s;
    float cx = cands[(b * Ch + c) * 2 + 0], cy = cands[(b * Ch + c) * 2 + 1];
    for (int d = tid; d < Dh; d += 256)
        cv[d] = W_cand[d * 2] * cx + W_cand[d * 2 + 1] * cy + b_cand[d];
    __syncthreads();
    float ls = 0.f;
    for (int d = tid; d < Dh; d += 256) ls += cv[d];
    for (int m = 32; m; m >>= 1) ls += __shfl_xor(ls, m);
    if ((tid & 63) == 0) red[tid >> 6] = ls;
    __syncthreads();
    if (tid == 0) mu_s = (red[0] + red[1] + red[2] + red[3]) * (1.f / Dh);
    __syncthreads();
    float mu = mu_s;
    float lv = 0.f;
    for (int d = tid; d < Dh; d += 256) { float t = cv[d] - mu; lv += t * t; }
    for (int m = 32; m; m >>= 1) lv += __shfl_xor(lv, m);
    if ((tid & 63) == 0) red[4 + (tid >> 6)] = lv;
    __syncthreads();
    if (tid == 0) rs_s = rsqrtf((red[4] + red[5] + red[6] + red[7]) * (1.f / Dh) + 1e-12f);
    __syncthreads();
    float rs = rs_s;
    float dv = den[b * Ch + c];
#pragma unroll
    for (int j = 0; j < 3; ++j) {
        int d = tid + j * 256;
        float gm = (dv > 0.f) ? G[(size_t)(b * Ch + c) * Dh + d] : 0.f;
        float cn = (cv[d] - mu) * rs * ln_g[d] + ln_b[d];
        out[((size_t)(b * (Fh + Ch) + Fh + c)) * Dh + d] =
            cn * lang[((size_t)b * Lh) * Dh + d] + gm;
    }
}

extern "C" void kernel_launch(void* const* d_in, const int* in_sizes, int n_in,
                              void* d_out, int out_size, void* d_ws, size_t ws_size,
                              hipStream_t stream) {
    (void)in_sizes; (void)n_in; (void)out_size; (void)ws_size;
    const float* lang      = (const float*)d_in[0];
    const float* lang_cls  = (const float*)d_in[1];
    const float* frames    = (const float*)d_in[2];
    const float* cands     = (const float*)d_in[3];
    const float* grid_fts  = (const float*)d_in[4];
    const int*   grid_idx  = (const int*)d_in[5];
    const float* W_in      = (const float*)d_in[6];
    const float* W_out     = (const float*)d_in[7];
    const float* W_fc2     = (const float*)d_in[8];
    const float* b_fc2     = (const float*)d_in[9];
    const float* W_text    = (const float*)d_in[10];
    const float* b_text    = (const float*)d_in[11];
    const float* W_grid    = (const float*)d_in[12];
    const float* b_grid    = (const float*)d_in[13];
    const float* W_cand    = (const float*)d_in[14];
    const float* b_cand    = (const float*)d_in[15];
    const float* ln_g      = (const float*)d_in[16];
    const float* ln_b      = (const float*)d_in[17];
    float* out = (float*)d_out;
    float* ws  = (float*)d_ws;

    float*    text  = ws;                       // 393216
    float*    tgt   = ws + 393216;              // 512
    float*    wbuf  = ws + 393728;              // 160000
    unsigned* m_u   = (unsigned*)(ws + 553728); // 288
    float*    den   = ws + 554016;              // 288
    int*      cnt   = (int*)(ws + 554304);      // 288
    int*      bn    = (int*)(ws + 554592);      // 589824
    float*    bp    = ws + 1144416;             // 589824
    float*    S     = ws + 1734240;             // 221184
    float*    G     = ws + 1955424;             // 221184
    uint4*    textH = (uint4*)(ws + 2176608);   // 196608 floats
    uint4*    textL = (uint4*)(ws + 2373216);   // 196608 floats

    hipLaunchKernelGGL(k_zero,   dim3(2), dim3(256), 0, stream, m_u, den, cnt);
    hipLaunchKernelGGL(k_text,   dim3(Bh * 32), dim3(256), 0, stream, lang, W_text, b_text, text);
    hipLaunchKernelGGL(k_tfrag,  dim3(192), dim3(256), 0, stream, text, textH, textL);
    hipLaunchKernelGGL(k_target, dim3(Bh), dim3(64), 0, stream, lang_cls, W_in, tgt);
    hipLaunchKernelGGL(k_frames, dim3(Bh * Fh), dim3(256), 0, stream,
                       frames, lang_cls, tgt, W_out, W_fc2, b_fc2, out);
    hipLaunchKernelGGL(k_w,      dim3((Nh + 127) / 128, Bh), dim3(256), 0, stream,
                       grid_fts, textH, textL, wbuf);
    hipLaunchKernelGGL(k_max,    dim3(79, Bh), dim3(256), 0, stream, wbuf, grid_idx, m_u);
    hipLaunchKernelGGL(k_den,    dim3(79, Bh), dim3(256), 0, stream, wbuf, grid_idx, m_u, den);
    hipLaunchKernelGGL(k_pc,     dim3(79, Bh), dim3(256), 0, stream,
                       wbuf, grid_idx, m_u, den, cnt, bn, bp);
    hipLaunchKernelGGL(k_S3,     dim3(Ch, 3, Bh), dim3(256), 0, stream,
                       grid_fts, cnt, bn, bp, S);
    hipLaunchKernelGGL(k_gg,     dim3(108, Bh), dim3(256), 0, stream, S, W_grid, b_grid, G);
    hipLaunchKernelGGL(k_final,  dim3(Bh * Ch), dim3(256), 0, stream,
                       G, den, cands, W_cand, b_cand, ln_g, ln_b, lang, out);
}

// Round 4
// 401.316 us; speedup vs baseline: 2.4747x; 1.0491x over previous
//
#include <hip/hip_runtime.h>
#include <math.h>

#define Bh 8
#define Lh 64
#define Dh 768
#define Fh 50
#define Ph 49
#define Ah 49
#define Nh 20000
#define Ch 36
#define CAP 2048
#define NCH 8
#define CUT 1e-7f

typedef __bf16 bf16x8 __attribute__((ext_vector_type(8)));
typedef float f32x4 __attribute__((ext_vector_type(4)));
union U { uint4 u; bf16x8 v; };

__device__ __forceinline__ void cvt2(float a0, float a1, unsigned& h, unsigned& l) {
    unsigned u0 = __float_as_uint(a0), u1 = __float_as_uint(a1);
    unsigned h0 = u0 & 0xFFFF0000u, h1 = u1 & 0xFFFF0000u;
    h = (h0 >> 16) | h1;
    float l0 = a0 - __uint_as_float(h0);
    float l1 = a1 - __uint_as_float(h1);
    l = (__float_as_uint(l0) >> 16) | (__float_as_uint(l1) & 0xFFFF0000u);
}

__device__ __forceinline__ void cvt8(float4 p, float4 q, bf16x8& h8, bf16x8& l8) {
    U h, l;
    cvt2(p.x, p.y, h.u.x, l.u.x);
    cvt2(p.z, p.w, h.u.y, l.u.y);
    cvt2(q.x, q.y, h.u.z, l.u.z);
    cvt2(q.z, q.w, h.u.w, l.u.w);
    h8 = h.v; l8 = l.v;
}

__device__ __forceinline__ float dec_max(unsigned u) {
    if (u == 0u) return 0.f;
    return (u & 0x80000000u) ? __uint_as_float(u ^ 0x80000000u) : __uint_as_float(~u);
}

// ---------------- zero small accumulators ----------------
__global__ void k_zero(unsigned* __restrict__ m_u, float* __restrict__ den,
                       int* __restrict__ cnt) {
    int i = blockIdx.x * 256 + threadIdx.x;
    if (i < Bh * Ch) { m_u[i] = 0u; den[i] = 0.f; cnt[i] = 0; }
}

// ---------------- text = lang @ W_text.T + b_text ----------------
__global__ __launch_bounds__(256) void k_text(const float* __restrict__ lang,
                                              const float* __restrict__ Wt,
                                              const float* __restrict__ bt,
                                              float* __restrict__ text) {
    int b  = blockIdx.x >> 5;
    int l0 = (blockIdx.x & 31) * 2;
    int tid = threadIdx.x;
    __shared__ float ls[2][Dh];
    for (int i = tid; i < 2 * Dh; i += 256)
        ls[i / Dh][i % Dh] = lang[((size_t)(b * Lh + l0 + i / Dh)) * Dh + (i % Dh)];
    __syncthreads();
    float acc[2][3] = {{0.f, 0.f, 0.f}, {0.f, 0.f, 0.f}};
    for (int k = 0; k < Dh; k += 4) {
        float4 v0 = *(const float4*)&ls[0][k];
        float4 v1 = *(const float4*)&ls[1][k];
#pragma unroll
        for (int j = 0; j < 3; ++j) {
            int d = tid + j * 256;
            float4 wv = *(const float4*)&Wt[(size_t)d * Dh + k];
            acc[0][j] += wv.x * v0.x + wv.y * v0.y + wv.z * v0.z + wv.w * v0.w;
            acc[1][j] += wv.x * v1.x + wv.y * v1.y + wv.z * v1.z + wv.w * v1.w;
        }
    }
#pragma unroll
    for (int li = 0; li < 2; ++li)
#pragma unroll
        for (int j = 0; j < 3; ++j) {
            int d = tid + j * 256;
            text[((size_t)(b * Lh + l0 + li)) * Dh + d] = acc[li][j] + bt[d];
        }
}

// ---------------- text -> fragment-major bf16 hi/lo ----------------
__global__ __launch_bounds__(256) void k_tfrag(const float* __restrict__ text,
                                               uint4* __restrict__ textH,
                                               uint4* __restrict__ textL) {
    int gid = blockIdx.x * 256 + threadIdx.x;  // 192*256 = 49152 exact
    int l  = gid & 63;
    int ct = (gid >> 6) & 3;
    int bk = gid >> 8;             // b*24 + ks
    int b  = bk / 24, ks = bk % 24;
    const float* src = text + ((size_t)(b * Lh + ct * 16 + (l & 15))) * Dh
                     + ks * 32 + (l >> 4) * 8;
    float4 p = *(const float4*)src;
    float4 q = *(const float4*)(src + 4);
    U h, lo;
    cvt2(p.x, p.y, h.u.x, lo.u.x);
    cvt2(p.z, p.w, h.u.y, lo.u.y);
    cvt2(q.x, q.y, h.u.z, lo.u.z);
    cvt2(q.z, q.w, h.u.w, lo.u.w);
    textH[gid] = h.u;
    textL[gid] = lo.u;
}

// ---------------- frames attention path (incl. target) -> out[b, 0..F) ----------------
__global__ __launch_bounds__(256) void k_frames(const float* __restrict__ frames,
                                                const float* __restrict__ lang_cls,
                                                const float* __restrict__ W_in,
                                                const float* __restrict__ W_out,
                                                const float* __restrict__ W_fc2,
                                                const float* __restrict__ b_fc2,
                                                float* __restrict__ out) {
    int b = blockIdx.x / Fh, f = blockIdx.x % Fh;
    int tid = threadIdx.x;
    __shared__ float fr[Ph * Ah];
    __shared__ float tg[Ah], cl[Ah], at[Ph], wc[Ah], af[Ah];
    const float* fp = frames + ((size_t)(b * Fh + f)) * (Ph * Ah);
    for (int i = tid; i < Ph * Ah; i += 256) fr[i] = fp[i];
    if (tid < Ah) {
        cl[tid] = lang_cls[b * Ah + tid];
        float s = 0.f;
        for (int k = 0; k < Ah; ++k) s += lang_cls[b * Ah + k] * W_in[tid * Ah + k];
        tg[tid] = s;
    }
    __syncthreads();
    if (tid < Ph) {
        float s = 0.f;
        for (int a = 0; a < Ah; ++a) s += fr[tid * Ah + a] * tg[a];
        at[tid] = s;
    }
    __syncthreads();
    if (tid < 64) {
        float raw = (tid < Ph) ? at[tid] : -3.4e38f;
        float v = raw;
        for (int m = 32; m; m >>= 1) v = fmaxf(v, __shfl_xor(v, m));
        float e = (tid < Ph) ? expf(raw - v) : 0.f;
        float s = e;
        for (int m = 32; m; m >>= 1) s += __shfl_xor(s, m);
        if (tid < Ph) at[tid] = e / s;
    }
    __syncthreads();
    if (tid < Ah) {
        float s = 0.f;
        for (int p = 0; p < Ph; ++p) s += at[p] * fr[p * Ah + tid];
        wc[tid] = s;
    }
    __syncthreads();
    if (tid < Ah) {
        float s = 0.f;
        for (int a = 0; a < Ah; ++a)
            s += wc[a] * W_out[tid * (2 * Ah) + a] + cl[a] * W_out[tid * (2 * Ah) + Ah + a];
        af[tid] = tanhf(s);
    }
    __syncthreads();
    for (int d = tid; d < Dh; d += 256) {
        float s = b_fc2[d];
        for (int j = 0; j < Ah; ++j) s += af[j] * W_fc2[d * Ah + j];
        out[((size_t)(b * (Fh + Ch) + f)) * Dh + d] = s;
    }
}

// ---------------- w[b,n] via split-bf16 MFMA, register double-buffered ----------------
__global__ __launch_bounds__(256) void k_w(const float* __restrict__ grid,
                                           const uint4* __restrict__ textH,
                                           const uint4* __restrict__ textL,
                                           float* __restrict__ w) {
    int b = blockIdx.y;
    int tid = threadIdx.x;
    int wv = tid >> 6, l = tid & 63;
    int nb = blockIdx.x * 128 + wv * 32;
    int r0 = nb + (l & 15);
    int r1 = r0 + 16;
    int r0c = r0 < Nh ? r0 : Nh - 1;
    int r1c = r1 < Nh ? r1 : Nh - 1;
    const float4* pa0 = (const float4*)(grid + ((size_t)b * Nh + r0c) * Dh) + ((l >> 4) * 2);
    const float4* pa1 = (const float4*)(grid + ((size_t)b * Nh + r1c) * Dh) + ((l >> 4) * 2);
    const uint4* pbh = textH + ((size_t)b * 24 * 4 * 64) + l;
    const uint4* pbl = textL + ((size_t)b * 24 * 4 * 64) + l;

    f32x4 acc[2][4];
#pragma unroll
    for (int i = 0; i < 2; ++i)
#pragma unroll
        for (int j = 0; j < 4; ++j) acc[i][j] = (f32x4){0.f, 0.f, 0.f, 0.f};

    // prologue: load iteration 0
    float4 x00 = pa0[0], x01 = pa0[1], x10 = pa1[0], x11 = pa1[1];
    uint4 bh0 = pbh[0],   bh1 = pbh[64],  bh2 = pbh[128], bh3 = pbh[192];
    uint4 bl0 = pbl[0],   bl1 = pbl[64],  bl2 = pbl[128], bl3 = pbl[192];

    for (int ks = 0; ks < 24; ++ks) {
        int ksn = (ks + 1 < 24) ? ks + 1 : 23;
        // prefetch next iteration (issued before current MFMAs)
        float4 nx00 = pa0[ksn * 8], nx01 = pa0[ksn * 8 + 1];
        float4 nx10 = pa1[ksn * 8], nx11 = pa1[ksn * 8 + 1];
        uint4 nbh0 = pbh[ksn * 256 +   0], nbh1 = pbh[ksn * 256 +  64];
        uint4 nbh2 = pbh[ksn * 256 + 128], nbh3 = pbh[ksn * 256 + 192];
        uint4 nbl0 = pbl[ksn * 256 +   0], nbl1 = pbl[ksn * 256 +  64];
        uint4 nbl2 = pbl[ksn * 256 + 128], nbl3 = pbl[ksn * 256 + 192];

        bf16x8 ah0, al0, ah1, al1;
        cvt8(x00, x01, ah0, al0);
        cvt8(x10, x11, ah1, al1);
        uint4 bhu[4] = {bh0, bh1, bh2, bh3};
        uint4 blu[4] = {bl0, bl1, bl2, bl3};
#pragma unroll
        for (int ct = 0; ct < 4; ++ct) {
            U ubh, ubl; ubh.u = bhu[ct]; ubl.u = blu[ct];
            bf16x8 bh = ubh.v, bl = ubl.v;
            acc[0][ct] = __builtin_amdgcn_mfma_f32_16x16x32_bf16(ah0, bh, acc[0][ct], 0, 0, 0);
            acc[0][ct] = __builtin_amdgcn_mfma_f32_16x16x32_bf16(al0, bh, acc[0][ct], 0, 0, 0);
            acc[0][ct] = __builtin_amdgcn_mfma_f32_16x16x32_bf16(ah0, bl, acc[0][ct], 0, 0, 0);
            acc[1][ct] = __builtin_amdgcn_mfma_f32_16x16x32_bf16(ah1, bh, acc[1][ct], 0, 0, 0);
            acc[1][ct] = __builtin_amdgcn_mfma_f32_16x16x32_bf16(al1, bh, acc[1][ct], 0, 0, 0);
            acc[1][ct] = __builtin_amdgcn_mfma_f32_16x16x32_bf16(ah1, bl, acc[1][ct], 0, 0, 0);
        }
        x00 = nx00; x01 = nx01; x10 = nx10; x11 = nx11;
        bh0 = nbh0; bh1 = nbh1; bh2 = nbh2; bh3 = nbh3;
        bl0 = nbl0; bl1 = nbl1; bl2 = nbl2; bl3 = nbl3;
    }

#pragma unroll
    for (int rt = 0; rt < 2; ++rt) {
        float m[4];
#pragma unroll
        for (int r = 0; r < 4; ++r) {
            m[r] = fmaxf(fmaxf(acc[rt][0][r], acc[rt][1][r]),
                         fmaxf(acc[rt][2][r], acc[rt][3][r]));
            m[r] = fmaxf(m[r], __shfl_xor(m[r], 1));
            m[r] = fmaxf(m[r], __shfl_xor(m[r], 2));
            m[r] = fmaxf(m[r], __shfl_xor(m[r], 4));
            m[r] = fmaxf(m[r], __shfl_xor(m[r], 8));
        }
        if ((l & 15) == 0) {
#pragma unroll
            for (int r = 0; r < 4; ++r) {
                int row = nb + rt * 16 + (l >> 4) * 4 + r;
                if (row < Nh) w[b * Nh + row] = m[r];
            }
        }
    }
}

// ---------------- per-cell max (pass 1) ----------------
__global__ __launch_bounds__(256) void k_max(const float* __restrict__ w,
                                             const int* __restrict__ gi,
                                             unsigned* __restrict__ m_u) {
    int b = blockIdx.y;
    int n = blockIdx.x * 256 + threadIdx.x;
    __shared__ unsigned mu[Ch];
    if (threadIdx.x < Ch) mu[threadIdx.x] = 0u;
    __syncthreads();
    if (n < Nh) {
        float v = w[b * Nh + n];
        unsigned u = __float_as_uint(v);
        u = (u & 0x80000000u) ? ~u : (u | 0x80000000u);
        atomicMax(&mu[gi[b * Nh + n]], u);
    }
    __syncthreads();
    if (threadIdx.x < Ch && mu[threadIdx.x])
        atomicMax(&m_u[b * Ch + threadIdx.x], mu[threadIdx.x]);
}

// ---------------- per-cell exp-sum (pass 2) ----------------
__global__ __launch_bounds__(256) void k_den(const float* __restrict__ w,
                                             const int* __restrict__ gi,
                                             const unsigned* __restrict__ m_u,
                                             float* __restrict__ den) {
    int b = blockIdx.y;
    int n = blockIdx.x * 256 + threadIdx.x;
    __shared__ float dn[Ch];
    if (threadIdx.x < Ch) dn[threadIdx.x] = 0.f;
    __syncthreads();
    if (n < Nh) {
        int c = gi[b * Nh + n];
        float m = dec_max(m_u[b * Ch + c]);
        atomicAdd(&dn[c], expf(w[b * Nh + n] - m));
    }
    __syncthreads();
    if (threadIdx.x < Ch && dn[threadIdx.x] != 0.f)
        atomicAdd(&den[b * Ch + threadIdx.x], dn[threadIdx.x]);
}

// ---------------- p + compaction into per-(b,c) buckets ----------------
__global__ __launch_bounds__(256) void k_pc(const float* __restrict__ w,
                                            const int* __restrict__ gi,
                                            const unsigned* __restrict__ m_u,
                                            const float* __restrict__ den,
                                            int* __restrict__ cnt,
                                            int* __restrict__ bn,
                                            float* __restrict__ bp) {
    int b = blockIdx.y;
    int n = blockIdx.x * 256 + threadIdx.x;
    if (n >= Nh) return;
    int c = gi[b * Nh + n];
    float dv = den[b * Ch + c];
    if (dv <= 0.f) return;
    float pv = expf(w[b * Nh + n] - dec_max(m_u[b * Ch + c])) / dv;
    if (pv > CUT) {
        int pos = atomicAdd(&cnt[b * Ch + c], 1);
        if (pos < CAP) {
            bn[(b * Ch + c) * CAP + pos] = n;
            bp[(b * Ch + c) * CAP + pos] = pv;
        }
    }
}

// ---------------- chunked segment weighted sums -> Spart[b][c][ch][d] ----------------
__global__ __launch_bounds__(256) void k_S3(const float* __restrict__ grid,
                                            const int* __restrict__ cnt,
                                            const int* __restrict__ bn,
                                            const float* __restrict__ bp,
                                            float* __restrict__ Spart) {
    int c = blockIdx.x, dq = blockIdx.y;
    int b = blockIdx.z >> 3, ch = blockIdx.z & 7;
    int d = dq * 256 + threadIdx.x;
    int len = cnt[b * Ch + c]; if (len > CAP) len = CAP;
    int i0 = ch * (CAP / NCH);
    int i1 = i0 + (CAP / NCH); if (i1 > len) i1 = len;
    size_t base = (size_t)(b * Ch + c) * CAP;
    size_t po = ((size_t)(b * Ch + c) * NCH + ch) * Dh + d;
    const float* gb = grid + (size_t)b * Nh * Dh + d;
    float a[8] = {0.f, 0.f, 0.f, 0.f, 0.f, 0.f, 0.f, 0.f};
    int i = i0;
    for (; i + 8 <= i1; i += 8) {
        int nn[8]; float pp[8];
#pragma unroll
        for (int j = 0; j < 8; ++j) { nn[j] = bn[base + i + j]; pp[j] = bp[base + i + j]; }
#pragma unroll
        for (int j = 0; j < 8; ++j) a[j] += pp[j] * gb[(size_t)nn[j] * Dh];
    }
    for (; i < i1; ++i) a[0] += bp[base + i] * gb[(size_t)bn[base + i] * Dh];
    Spart[po] = ((a[0] + a[1]) + (a[2] + a[3])) + ((a[4] + a[5]) + (a[6] + a[7]));
}

// ---------------- reduce 8 chunk partials -> S ----------------
__global__ __launch_bounds__(256) void k_red(const float* __restrict__ Spart,
                                             float* __restrict__ S) {
    int bc = blockIdx.x, dq = blockIdx.y;
    int d = dq * 256 + threadIdx.x;
    float s = 0.f;
#pragma unroll
    for (int ch = 0; ch < NCH; ++ch)
        s += Spart[((size_t)bc * NCH + ch) * Dh + d];
    S[(size_t)bc * Dh + d] = s;
}

// ---------------- G = S @ W_grid.T + b_grid ----------------
__global__ __launch_bounds__(256) void k_gg(const float* __restrict__ S,
                                            const float* __restrict__ Wg,
                                            const float* __restrict__ bg,
                                            float* __restrict__ G) {
    int b = blockIdx.y;
    int cq = blockIdx.x / 12, dt = blockIdx.x % 12;
    int c = cq * 4 + (threadIdx.x >> 6);
    int d = dt * 64 + (threadIdx.x & 63);
    const float* sr = S + (size_t)(b * Ch + c) * Dh;
    const float* wr = Wg + (size_t)d * Dh;
    float acc = 0.f;
    for (int k = 0; k < Dh; k += 4) {
        float4 s4 = *(const float4*)&sr[k];
        float4 w4 = *(const float4*)&wr[k];
        acc += s4.x * w4.x + s4.y * w4.y + s4.z * w4.z + s4.w * w4.w;
    }
    G[(size_t)(b * Ch + c) * Dh + d] = acc + bg[d];
}

// ---------------- final: candidate LN + combine ----------------
__global__ __launch_bounds__(256) void k_final(const float* __restrict__ G,
                                               const float* __restrict__ den,
                                               const float* __restrict__ cands,
                                               const float* __restrict__ W_cand,
                                               const float* __restrict__ b_cand,
                                               const float* __restrict__ ln_g,
                                               const float* __restrict__ ln_b,
                                               const float* __restrict__ lang,
                                               float* __restrict__ out) {
    int b = blockIdx.x / Ch, c = blockIdx.x % Ch;
    int tid = threadIdx.x;
    __shared__ float cv[Dh];
    __shared__ float red[8];
    __shared__ float mu_s, rs_s;
    float cx = cands[(b * Ch + c) * 2 + 0], cy = cands[(b * Ch + c) * 2 + 1];
    for (int d = tid; d < Dh; d += 256)
        cv[d] = W_cand[d * 2] * cx + W_cand[d * 2 + 1] * cy + b_cand[d];
    __syncthreads();
    float ls = 0.f;
    for (int d = tid; d < Dh; d += 256) ls += cv[d];
    for (int m = 32; m; m >>= 1) ls += __shfl_xor(ls, m);
    if ((tid & 63) == 0) red[tid >> 6] = ls;
    __syncthreads();
    if (tid == 0) mu_s = (red[0] + red[1] + red[2] + red[3]) * (1.f / Dh);
    __syncthreads();
    float mu = mu_s;
    float lv = 0.f;
    for (int d = tid; d < Dh; d += 256) { float t = cv[d] - mu; lv += t * t; }
    for (int m = 32; m; m >>= 1) lv += __shfl_xor(lv, m);
    if ((tid & 63) == 0) red[4 + (tid >> 6)] = lv;
    __syncthreads();
    if (tid == 0) rs_s = rsqrtf((red[4] + red[5] + red[6] + red[7]) * (1.f / Dh) + 1e-12f);
    __syncthreads();
    float rs = rs_s;
    float dv = den[b * Ch + c];
#pragma unroll
    for (int j = 0; j < 3; ++j) {
        int d = tid + j * 256;
        float gm = (dv > 0.f) ? G[(size_t)(b * Ch + c) * Dh + d] : 0.f;
        float cn = (cv[d] - mu) * rs * ln_g[d] + ln_b[d];
        out[((size_t)(b * (Fh + Ch) + Fh + c)) * Dh + d] =
            cn * lang[((size_t)b * Lh) * Dh + d] + gm;
    }
}

extern "C" void kernel_launch(void* const* d_in, const int* in_sizes, int n_in,
                              void* d_out, int out_size, void* d_ws, size_t ws_size,
                              hipStream_t stream) {
    (void)in_sizes; (void)n_in; (void)out_size; (void)ws_size;
    const float* lang      = (const float*)d_in[0];
    const float* lang_cls  = (const float*)d_in[1];
    const float* frames    = (const float*)d_in[2];
    const float* cands     = (const float*)d_in[3];
    const float* grid_fts  = (const float*)d_in[4];
    const int*   grid_idx  = (const int*)d_in[5];
    const float* W_in      = (const float*)d_in[6];
    const float* W_out     = (const float*)d_in[7];
    const float* W_fc2     = (const float*)d_in[8];
    const float* b_fc2     = (const float*)d_in[9];
    const float* W_text    = (const float*)d_in[10];
    const float* b_text    = (const float*)d_in[11];
    const float* W_grid    = (const float*)d_in[12];
    const float* b_grid    = (const float*)d_in[13];
    const float* W_cand    = (const float*)d_in[14];
    const float* b_cand    = (const float*)d_in[15];
    const float* ln_g      = (const float*)d_in[16];
    const float* ln_b      = (const float*)d_in[17];
    float* out = (float*)d_out;
    float* ws  = (float*)d_ws;

    float*    text  = ws;                       // 393216
    float*    wbuf  = ws + 393216;              // 160000
    unsigned* m_u   = (unsigned*)(ws + 553216); // 288
    float*    den   = ws + 553504;              // 288
    int*      cnt   = (int*)(ws + 553792);      // 288
    int*      bn    = (int*)(ws + 554080);      // 589824
    float*    bp    = ws + 1143904;             // 589824
    float*    S     = ws + 1733728;             // 221184
    float*    G     = ws + 1954912;             // 221184
    uint4*    textH = (uint4*)(ws + 2176096);   // 196608 floats (16B aligned)
    uint4*    textL = (uint4*)(ws + 2372704);   // 196608 floats (16B aligned)
    float*    Spart = ws + 2569312;             // 8*36*8*768 = 1769472

    hipLaunchKernelGGL(k_zero,   dim3(2), dim3(256), 0, stream, m_u, den, cnt);
    hipLaunchKernelGGL(k_text,   dim3(Bh * 32), dim3(256), 0, stream, lang, W_text, b_text, text);
    hipLaunchKernelGGL(k_tfrag,  dim3(192), dim3(256), 0, stream, text, textH, textL);
    hipLaunchKernelGGL(k_frames, dim3(Bh * Fh), dim3(256), 0, stream,
                       frames, lang_cls, W_in, W_out, W_fc2, b_fc2, out);
    hipLaunchKernelGGL(k_w,      dim3((Nh + 127) / 128, Bh), dim3(256), 0, stream,
                       grid_fts, textH, textL, wbuf);
    hipLaunchKernelGGL(k_max,    dim3(79, Bh), dim3(256), 0, stream, wbuf, grid_idx, m_u);
    hipLaunchKernelGGL(k_den,    dim3(79, Bh), dim3(256), 0, stream, wbuf, grid_idx, m_u, den);
    hipLaunchKernelGGL(k_pc,     dim3(79, Bh), dim3(256), 0, stream,
                       wbuf, grid_idx, m_u, den, cnt, bn, bp);
    hipLaunchKernelGGL(k_S3,     dim3(Ch, 3, Bh * NCH), dim3(256), 0, stream,
                       grid_fts, cnt, bn, bp, Spart);
    hipLaunchKernelGGL(k_red,    dim3(Bh * Ch, 3), dim3(256), 0, stream, Spart, S);
    hipLaunchKernelGGL(k_gg,     dim3(108, Bh), dim3(256), 0, stream, S, W_grid, b_grid, G);
    hipLaunchKernelGGL(k_final,  dim3(Bh * Ch), dim3(256), 0, stream,
                       G, den, cands, W_cand, b_cand, ln_g, ln_b, lang, out);
}